// Round 13
// baseline (29506.473 us; speedup 1.0000x reference)
//
#include <hip/hip_runtime.h>

typedef unsigned short u16;
typedef unsigned int u32;
typedef __attribute__((ext_vector_type(8))) short bf16x8;
typedef __attribute__((ext_vector_type(4))) float f32x4;
typedef __attribute__((ext_vector_type(4))) unsigned int u32x4;

#define B_ 512
#define T_ 1024
#define F_ 128
#define H_ 512
#define G_ 2048
#define LH_ 1024

#define MFMA16(a,b,c) (c) = __builtin_amdgcn_mfma_f32_16x16x32_bf16((a),(b),(c),0,0,0)

__device__ __forceinline__ u16 f2bf(float f) {
  unsigned u = __float_as_uint(f);
  unsigned r = (u + 0x7fffu + ((u >> 16) & 1u)) >> 16;
  return (u16)r;
}
__device__ __forceinline__ float bf2f(u16 h) {
  return __uint_as_float(((unsigned)h) << 16);
}

// ---------------- workspace layout (bytes) ----------------
constexpr size_t O_HPK     = 0;                               // u32 packed h, 2 bufs: 2 MB
constexpr size_t O_FL      = O_HPK + (size_t)2 * B_ * H_ * 4; // per-owner-wave flags (256*4 u32)
constexpr size_t O_MSET    = O_FL + 8192;                     // memset [0, O_MSET)
constexpr size_t O_WHH_HI  = O_MSET;
constexpr size_t O_WHH_LO  = O_WHH_HI + (size_t)G_ * H_ * 2;
constexpr size_t O_WIH_HI  = O_WHH_LO + (size_t)G_ * H_ * 2;
constexpr size_t O_WIH_LO  = O_WIH_HI + (size_t)G_ * F_ * 2;
constexpr size_t O_BIAS    = O_WIH_LO + (size_t)G_ * F_ * 2;
constexpr size_t O_HT      = O_BIAS + (size_t)G_ * 4;
constexpr size_t O_Z       = O_HT + (size_t)B_ * H_ * 4;

// ---------------- LDS layout ----------------
constexpr unsigned SM_WHH_LO = 65536;    // sWhhHi [64][512] u16 swizzled at 0
constexpr unsigned SM_XC     = 131072;   // gate-sum accumulator [2rt][2rf][4ct][4q][64l] f32 = 16 KB
constexpr unsigned SMEM_BYTES = 147456;

// ---------------- weight prep: permute + split to hi/lo bf16 ----------------
// permuted gate-col P = 64*nb + 16*g + u'  (unit u = 16*nb + u', g in {i,f,g,o})
__global__ void prep_weights(const float* __restrict__ Wih, const float* __restrict__ Whh,
                             const float* __restrict__ bih, const float* __restrict__ bhh,
                             u16* __restrict__ WhhHi, u16* __restrict__ WhhLo,
                             u16* __restrict__ WihHi, u16* __restrict__ WihLo,
                             float* __restrict__ bias) {
  int P = blockIdx.x;
  int nb = P >> 6, g = (P >> 4) & 3, u = P & 15;
  int orig = g * H_ + (nb << 4) + u;
  for (int k = threadIdx.x; k < H_; k += 128) {
    float w = Whh[(size_t)orig * H_ + k];
    u16 hi = f2bf(w);
    WhhHi[(size_t)P * H_ + k] = hi;
    WhhLo[(size_t)P * H_ + k] = f2bf(w - bf2f(hi));
  }
  {
    int k = threadIdx.x;
    float w = Wih[(size_t)orig * F_ + k];
    u16 hi = f2bf(w);
    WihHi[(size_t)P * F_ + k] = hi;
    WihLo[(size_t)P * F_ + k] = f2bf(w - bf2f(hi));
  }
  if (threadIdx.x == 0) bias[P] = bih[orig] + bhh[orig];
}

// ---------------- helpers ----------------
__device__ __forceinline__ u32x4 ald16(const u32* p) {   // agent-coherent 16B load
  u32x4 r;
  asm volatile("global_load_dwordx4 %0, %1, off sc1" : "=&v"(r) : "v"(p));
  return r;
}
__device__ __forceinline__ u32x4 pld16(const float* p) { // plain cacheable 16B load
  u32x4 r;
  asm volatile("global_load_dwordx4 %0, %1, off" : "=&v"(r) : "v"(p));
  return r;
}

__device__ __forceinline__ void unpack(u32x4 a, u32x4 b, bf16x8& hi, bf16x8& lo) {
  #pragma unroll
  for (int j = 0; j < 4; ++j) { hi[j] = (short)(a[j] & 0xffffu); lo[j] = (short)(a[j] >> 16); }
  #pragma unroll
  for (int j = 0; j < 4; ++j) { hi[4 + j] = (short)(b[j] & 0xffffu); lo[4 + j] = (short)(b[j] >> 16); }
}

__device__ __forceinline__ void cvt8(u32x4 a, u32x4 b, bf16x8& hi, bf16x8& lo) {
  #pragma unroll
  for (int j = 0; j < 8; ++j) {
    float f = __uint_as_float(j < 4 ? a[j] : b[j - 4]);
    u16 h = f2bf(f);
    hi[j] = (short)h;
    lo[j] = (short)f2bf(f - bf2f(h));
  }
}

// full-row XOR swizzle (conflict-free, verified round 9)
__device__ __forceinline__ bf16x8 ldB(const u16* base, int r, int k8) {
  return *(const bf16x8*)(base + r * 512 + ((k8 ^ (r & 63)) << 3));
}

// ---------------- persistent LSTM kernel ----------------
// grid 256 = 8 row-groups (m = bid&7) x 32 unit-blocks (nb = bid>>3)
// 512 threads = 8 waves = 2 row-tiles (rt, 32 rows each) x 4 K-quarters (cp)
__global__ __launch_bounds__(512, 1) void lstm_persistent(
    const float* __restrict__ x,
    const u16* __restrict__ WhhHi, const u16* __restrict__ WhhLo,
    const u16* __restrict__ WihHi, const u16* __restrict__ WihLo,
    const float* __restrict__ bias,
    u32* __restrict__ hPk, u32* __restrict__ fl, float* __restrict__ hT) {
  extern __shared__ char smem[];
  u16* sWhhHi  = (u16*)(smem);
  u16* sWhhLo  = (u16*)(smem + SM_WHH_LO);
  float* sXc   = (float*)(smem + SM_XC);

  const int tid = threadIdx.x;
  const int w = tid >> 6, l = tid & 63;
  const int m  = blockIdx.x & 7;
  const int nb = blockIdx.x >> 3;
  const int Pbase = 64 * nb;
  const int l15 = l & 15, l4 = l >> 4;
  const int rt = w >> 2, cp = w & 3;
  const int owner = ((cp & 1) == 0);     // cp 0 and 2 run the elementwise
  const int own_rf = cp >> 1;            // cp0 -> rowfrag 0, cp2 -> rowfrag 1

  // ---- one-time: resident Whh slice (swizzled r&63) ----
  for (int i = tid; i < 4096; i += 512) {
    int r = i >> 6, k8 = i & 63;
    unsigned dst = r * 512 + ((k8 ^ (r & 63)) << 3);
    *(bf16x8*)(sWhhHi + dst) = *(const bf16x8*)(WhhHi + (size_t)(Pbase + r) * H_ + k8 * 8);
    *(bf16x8*)(sWhhLo + dst) = *(const bf16x8*)(WhhLo + (size_t)(Pbase + r) * H_ + k8 * 8);
  }

  // ---- one-time: bias into registers (gate g for unit l15) ----
  float bg4[4];
  #pragma unroll
  for (int g = 0; g < 4; ++g) bg4[g] = bias[Pbase + 16 * g + l15];

  // ---- one-time: Wih fragments (4 gate-tiles x this F-quarter chunk, hi+lo) ----
  bf16x8 wfh[4], wfl[4];
  #pragma unroll
  for (int ct = 0; ct < 4; ++ct) {
    int gcol = 16 * ct + l15;
    int k8i = 4 * cp + l4;
    wfh[ct] = *(const bf16x8*)(WihHi + (size_t)(Pbase + gcol) * F_ + k8i * 8);
    wfl[ct] = *(const bf16x8*)(WihLo + (size_t)(Pbase + gcol) * F_ + k8i * 8);
  }
  __syncthreads();

  const int arow0 = 64 * m + 32 * rt + l15;   // rowfrag 0 row for this lane
  const int arow1 = arow0 + 16;               // rowfrag 1

  // prologue: x(0) prefetch (both rowfrags, this wave's F-quarter), drained
  u32x4 xv[4];
  {
    const float* xr0 = x + (size_t)arow0 * T_ * F_ + 32 * cp + 8 * l4;
    const float* xr1 = x + (size_t)arow1 * T_ * F_ + 32 * cp + 8 * l4;
    xv[0] = pld16(xr0); xv[1] = pld16(xr0 + 4);
    xv[2] = pld16(xr1); xv[3] = pld16(xr1 + 4);
  }
  asm volatile("s_waitcnt vmcnt(0)" ::: "memory");

  float cr[4] = {0.f, 0.f, 0.f, 0.f};   // cell state (owner waves only)

  #pragma unroll 1
  for (int t = 0; t < T_; ++t) {
    const u32* hcur = hPk + (size_t)(t & 1) * B_ * H_;
    u32* hnxt = hPk + (size_t)((t & 1) ^ 1) * B_ * H_;

    f32x4 acc[2][4];
    #pragma unroll
    for (int rf = 0; rf < 2; ++rf)
      #pragma unroll
      for (int ct = 0; ct < 4; ++ct) acc[rf][ct] = f32x4{0.f, 0.f, 0.f, 0.f};

    // ---- poll the 16 producer-wave flags of this K-quarter (lanes 0..15) ----
    if (t > 0 && l < 16) {
      const u32* fp = fl + (size_t)(m * 32 + 8 * cp + (l >> 1)) * 4 + 2 * rt + (l & 1);
      long fuse = 400000000;
      while (__hip_atomic_load(fp, __ATOMIC_RELAXED, __HIP_MEMORY_SCOPE_AGENT) < (u32)t) {
        __builtin_amdgcn_s_sleep(1);
        if (--fuse == 0) break;
      }
    }

    // ---- issue ALL 4 h chunks x 2 rowfrags (16 loads) upfront ----
    u32x4 A0a[4], A0b[4], A1a[4], A1b[4];
    const u32* hr0 = hcur + (size_t)arow0 * H_ + 128 * cp + 8 * l4;
    const u32* hr1 = hcur + (size_t)arow1 * H_ + 128 * cp + 8 * l4;
    if (t > 0) {
      #pragma unroll
      for (int c = 0; c < 4; ++c) {
        A0a[c] = ald16(hr0 + c * 32);
        A0b[c] = ald16(hr0 + c * 32 + 4);
        A1a[c] = ald16(hr1 + c * 32);
        A1b[c] = ald16(hr1 + c * 32 + 4);
      }
    }

    // ---- x-part (1 chunk of this F-quarter, both rowfrags) ----
    {
      bf16x8 xh, xl;
      cvt8(xv[0], xv[1], xh, xl);
      #pragma unroll
      for (int ct = 0; ct < 4; ++ct) {
        MFMA16(xh, wfh[ct], acc[0][ct]); MFMA16(xl, wfh[ct], acc[0][ct]); MFMA16(xh, wfl[ct], acc[0][ct]);
      }
      cvt8(xv[2], xv[3], xh, xl);
      #pragma unroll
      for (int ct = 0; ct < 4; ++ct) {
        MFMA16(xh, wfh[ct], acc[1][ct]); MFMA16(xl, wfh[ct], acc[1][ct]); MFMA16(xh, wfl[ct], acc[1][ct]);
      }
    }

    // ---- h-part: 4 K=32 chunks, B-fragments reused across 2 rowfrags ----
    if (t > 0) {
      #pragma unroll
      for (int c = 0; c < 4; ++c) {
        if (c == 0)      asm volatile("s_waitcnt vmcnt(12)");
        else if (c == 1) asm volatile("s_waitcnt vmcnt(8)");
        else if (c == 2) asm volatile("s_waitcnt vmcnt(4)");
        else             asm volatile("s_waitcnt vmcnt(0)");
        __builtin_amdgcn_sched_barrier(0);
        bf16x8 ah0, al0, ah1, al1;
        unpack(A0a[c], A0b[c], ah0, al0);
        unpack(A1a[c], A1b[c], ah1, al1);
        int k8 = 16 * cp + 4 * c + l4;
        #pragma unroll
        for (int ct = 0; ct < 4; ++ct) {
          bf16x8 bh = ldB(sWhhHi, 16 * ct + l15, k8);
          bf16x8 bl = ldB(sWhhLo, 16 * ct + l15, k8);
          MFMA16(ah0, bh, acc[0][ct]); MFMA16(al0, bh, acc[0][ct]); MFMA16(ah0, bl, acc[0][ct]);
          MFMA16(ah1, bh, acc[1][ct]); MFMA16(al1, bh, acc[1][ct]); MFMA16(ah1, bl, acc[1][ct]);
        }
      }
    }

    // ---- 4-way partial reduction: cp0 initializes, cp1..3 ds_add ----
    if (cp == 0) {
      #pragma unroll
      for (int rf = 0; rf < 2; ++rf)
        #pragma unroll
        for (int ct = 0; ct < 4; ++ct)
          #pragma unroll
          for (int q = 0; q < 4; ++q)
            sXc[(((rt * 2 + rf) * 4 + ct) * 4 + q) * 64 + l] = acc[rf][ct][q];
    }
    __syncthreads();   // A1: init writes visible
    if (cp != 0) {
      #pragma unroll
      for (int rf = 0; rf < 2; ++rf)
        #pragma unroll
        for (int ct = 0; ct < 4; ++ct)
          #pragma unroll
          for (int q = 0; q < 4; ++q)
            atomicAdd(&sXc[(((rt * 2 + rf) * 4 + ct) * 4 + q) * 64 + l], acc[rf][ct][q]);
    }
    __syncthreads();   // A2: sums complete

    // ---- owners snapshot their gate sums (before B so others can proceed) ----
    float pr[16];
    if (owner) {
      #pragma unroll
      for (int ct = 0; ct < 4; ++ct)
        #pragma unroll
        for (int q = 0; q < 4; ++q)
          pr[ct * 4 + q] = sXc[(((rt * 2 + own_rf) * 4 + ct) * 4 + q) * 64 + l];
    }
    __syncthreads();   // B: sXc free for next step's writers

    // ---- x(t+1) prefetch (all waves; drained by owner drain or next poll) ----
    {
      int tp = (t + 1 < T_) ? t + 1 : 0;
      const float* xr0 = x + ((size_t)arow0 * T_ + tp) * F_ + 32 * cp + 8 * l4;
      const float* xr1 = x + ((size_t)arow1 * T_ + tp) * F_ + 32 * cp + 8 * l4;
      xv[0] = pld16(xr0); xv[1] = pld16(xr0 + 4);
      xv[2] = pld16(xr1); xv[3] = pld16(xr1 + 4);
    }

    // ---- owners: elementwise (c in VGPRs), h store, drain, per-wave flag ----
    // overlaps with non-owner waves' next-step poll + h-load issue
    if (owner) {
      #pragma unroll
      for (int q = 0; q < 4; ++q) {
        float gi = pr[0 * 4 + q] + bg4[0];
        float gf = pr[1 * 4 + q] + bg4[1];
        float gg = pr[2 * 4 + q] + bg4[2];
        float go = pr[3 * 4 + q] + bg4[3];
        float ii = 1.f / (1.f + __expf(-gi));
        float ff = 1.f / (1.f + __expf(-gf));
        float gG = 1.f - 2.f / (__expf(2.f * gg) + 1.f);
        float oo = 1.f / (1.f + __expf(-go));
        float c = ff * cr[q] + ii * gG;
        cr[q] = c;
        float h = oo * (1.f - 2.f / (__expf(2.f * c) + 1.f));
        u16 hb = f2bf(h);
        u16 lb = f2bf(h - bf2f(hb));
        u32 pk = (u32)hb | ((u32)lb << 16);
        size_t idx = (size_t)(64 * m + 32 * rt + 16 * own_rf + 4 * l4 + q) * H_ + 16 * nb + l15;
        __hip_atomic_store(&hnxt[idx], pk, __ATOMIC_RELAXED, __HIP_MEMORY_SCOPE_AGENT);
        if (t == T_ - 1) hT[idx] = h;
      }
      asm volatile("s_waitcnt vmcnt(0)" ::: "memory");   // per-wave drain of own stores
      if (l == 0)
        __hip_atomic_store(&fl[(size_t)(m * 32 + nb) * 4 + 2 * rt + own_rf], (u32)(t + 1),
                           __ATOMIC_RELAXED, __HIP_MEMORY_SCOPE_AGENT);
    }
  }
}

// ---------------- head: z = relu(hT @ W1^T + b1) ----------------
__global__ __launch_bounds__(256) void head1(const float* __restrict__ hT,
                                             const float* __restrict__ W1,
                                             const float* __restrict__ b1,
                                             float* __restrict__ z) {
  __shared__ float sA[64][16];
  __shared__ float sBt[16][64];
  int tx = threadIdx.x & 15, ty = threadIdx.x >> 4;
  int row0 = blockIdx.y * 64, col0 = blockIdx.x * 64;
  float acc[4][4] = {};
  for (int k0 = 0; k0 < H_; k0 += 16) {
    int c = threadIdx.x >> 2, kk4 = (threadIdx.x & 3) * 4;
    float4 av = *(const float4*)(hT + (size_t)(row0 + c) * H_ + k0 + kk4);
    *(float4*)&sA[c][kk4] = av;
    float4 bv = *(const float4*)(W1 + (size_t)(col0 + c) * H_ + k0 + kk4);
    sBt[kk4 + 0][c] = bv.x; sBt[kk4 + 1][c] = bv.y;
    sBt[kk4 + 2][c] = bv.z; sBt[kk4 + 3][c] = bv.w;
    __syncthreads();
    #pragma unroll
    for (int kk = 0; kk < 16; ++kk) {
      float a0 = sA[ty * 4 + 0][kk], a1 = sA[ty * 4 + 1][kk];
      float a2 = sA[ty * 4 + 2][kk], a3 = sA[ty * 4 + 3][kk];
      float b0 = sBt[kk][tx * 4 + 0], b1v = sBt[kk][tx * 4 + 1];
      float b2v = sBt[kk][tx * 4 + 2], b3 = sBt[kk][tx * 4 + 3];
      acc[0][0] += a0 * b0; acc[0][1] += a0 * b1v; acc[0][2] += a0 * b2v; acc[0][3] += a0 * b3;
      acc[1][0] += a1 * b0; acc[1][1] += a1 * b1v; acc[1][2] += a1 * b2v; acc[1][3] += a1 * b3;
      acc[2][0] += a2 * b0; acc[2][1] += a2 * b1v; acc[2][2] += a2 * b2v; acc[2][3] += a2 * b3;
      acc[3][0] += a3 * b0; acc[3][1] += a3 * b1v; acc[3][2] += a3 * b2v; acc[3][3] += a3 * b3;
    }
    __syncthreads();
  }
  #pragma unroll
  for (int i = 0; i < 4; ++i)
    #pragma unroll
    for (int j = 0; j < 4; ++j) {
      int rr = row0 + ty * 4 + i, cc = col0 + tx * 4 + j;
      float v = acc[i][j] + b1[cc];
      z[(size_t)rr * LH_ + cc] = v > 0.f ? v : 0.f;
    }
}

// ---------------- head: out[b] = z[b,:] . W2 + b2 ----------------
__global__ __launch_bounds__(256) void head2(const float* __restrict__ z,
                                             const float* __restrict__ W2,
                                             const float* __restrict__ b2,
                                             float* __restrict__ out) {
  int b = blockIdx.x;
  float p = 0.f;
  for (int j = threadIdx.x; j < LH_; j += 256) p += z[(size_t)b * LH_ + j] * W2[j];
  #pragma unroll
  for (int off = 32; off > 0; off >>= 1) p += __shfl_down(p, off);
  __shared__ float red[4];
  if ((threadIdx.x & 63) == 0) red[threadIdx.x >> 6] = p;
  __syncthreads();
  if (threadIdx.x == 0) out[b] = red[0] + red[1] + red[2] + red[3] + b2[0];
}

// ---------------- launch ----------------
extern "C" void kernel_launch(void* const* d_in, const int* in_sizes, int n_in,
                              void* d_out, int out_size, void* d_ws, size_t ws_size,
                              hipStream_t stream) {
  const float* x    = (const float*)d_in[0];
  const float* Wih  = (const float*)d_in[1];
  const float* Whh  = (const float*)d_in[2];
  const float* bih  = (const float*)d_in[3];
  const float* bhh  = (const float*)d_in[4];
  const float* W1   = (const float*)d_in[5];
  const float* b1   = (const float*)d_in[6];
  const float* W2   = (const float*)d_in[7];
  const float* b2   = (const float*)d_in[8];

  char* ws = (char*)d_ws;
  u32* hPk      = (u32*)(ws + O_HPK);
  u32* fl       = (u32*)(ws + O_FL);
  u16* whhHi    = (u16*)(ws + O_WHH_HI);
  u16* whhLo    = (u16*)(ws + O_WHH_LO);
  u16* wihHi    = (u16*)(ws + O_WIH_HI);
  u16* wihLo    = (u16*)(ws + O_WIH_LO);
  float* bias   = (float*)(ws + O_BIAS);
  float* hT     = (float*)(ws + O_HT);
  float* zbuf   = (float*)(ws + O_Z);

  (void)hipMemsetAsync(ws, 0, O_MSET, stream);

  prep_weights<<<G_, 128, 0, stream>>>(Wih, Whh, bih, bhh, whhHi, whhLo, wihHi, wihLo, bias);

  (void)hipFuncSetAttribute((const void*)lstm_persistent,
                            hipFuncAttributeMaxDynamicSharedMemorySize, SMEM_BYTES);

  lstm_persistent<<<256, 512, SMEM_BYTES, stream>>>(x, whhHi, whhLo, wihHi, wihLo,
                                                    bias, hPk, fl, hT);

  head1<<<dim3(LH_ / 64, B_ / 64), 256, 0, stream>>>(hT, W1, b1, zbuf);
  head2<<<B_, 256, 0, stream>>>(zbuf, W2, b2, (float*)d_out);
}

// Round 14
// 14039.682 us; speedup vs baseline: 2.1016x; 2.1016x over previous
//
#include <hip/hip_runtime.h>

typedef unsigned short u16;
typedef unsigned int u32;
typedef __attribute__((ext_vector_type(8))) short bf16x8;
typedef __attribute__((ext_vector_type(4))) float f32x4;
typedef __attribute__((ext_vector_type(4))) unsigned int u32x4;

#define B_ 512
#define T_ 1024
#define F_ 128
#define H_ 512
#define G_ 2048
#define LH_ 1024

#define MFMA16(a,b,c) (c) = __builtin_amdgcn_mfma_f32_16x16x32_bf16((a),(b),(c),0,0,0)

__device__ __forceinline__ u16 f2bf(float f) {
  unsigned u = __float_as_uint(f);
  unsigned r = (u + 0x7fffu + ((u >> 16) & 1u)) >> 16;
  return (u16)r;
}
__device__ __forceinline__ float bf2f(u16 h) {
  return __uint_as_float(((unsigned)h) << 16);
}

// ---------------- workspace layout (bytes) ----------------
constexpr size_t O_HPK     = 0;                               // bf16 h, 2 bufs: 2*512*512*2 = 1 MB
constexpr size_t O_FL      = O_HPK + (size_t)2 * B_ * H_ * 2; // per-cp0-wave flags (256*4 u32)
constexpr size_t O_MSET    = O_FL + 8192;                     // memset [0, O_MSET)
constexpr size_t O_WHH_HI  = O_MSET;
constexpr size_t O_WHH_LO  = O_WHH_HI + (size_t)G_ * H_ * 2;
constexpr size_t O_WIH_HI  = O_WHH_LO + (size_t)G_ * H_ * 2;
constexpr size_t O_WIH_LO  = O_WIH_HI + (size_t)G_ * F_ * 2;
constexpr size_t O_BIAS    = O_WIH_LO + (size_t)G_ * F_ * 2;
constexpr size_t O_HT      = O_BIAS + (size_t)G_ * 4;
constexpr size_t O_Z       = O_HT + (size_t)B_ * H_ * 4;

// ---------------- LDS layout ----------------
constexpr unsigned SM_WHH_LO = 65536;    // sWhhHi [64][512] u16 swizzled at 0
constexpr unsigned SM_XC     = 131072;   // partial exchange, DOUBLE buffered: 2 x [4rt][16][64] f32
constexpr unsigned SMEM_BYTES = 163840;  // 160 KiB exactly (AITER-proven max)

// ---------------- weight prep: permute + split to hi/lo bf16 ----------------
// permuted gate-col P = 64*nb + 16*g + u'  (unit u = 16*nb + u', g in {i,f,g,o})
__global__ void prep_weights(const float* __restrict__ Wih, const float* __restrict__ Whh,
                             const float* __restrict__ bih, const float* __restrict__ bhh,
                             u16* __restrict__ WhhHi, u16* __restrict__ WhhLo,
                             u16* __restrict__ WihHi, u16* __restrict__ WihLo,
                             float* __restrict__ bias) {
  int P = blockIdx.x;
  int nb = P >> 6, g = (P >> 4) & 3, u = P & 15;
  int orig = g * H_ + (nb << 4) + u;
  for (int k = threadIdx.x; k < H_; k += 128) {
    float w = Whh[(size_t)orig * H_ + k];
    u16 hi = f2bf(w);
    WhhHi[(size_t)P * H_ + k] = hi;
    WhhLo[(size_t)P * H_ + k] = f2bf(w - bf2f(hi));
  }
  {
    int k = threadIdx.x;
    float w = Wih[(size_t)orig * F_ + k];
    u16 hi = f2bf(w);
    WihHi[(size_t)P * F_ + k] = hi;
    WihLo[(size_t)P * F_ + k] = f2bf(w - bf2f(hi));
  }
  if (threadIdx.x == 0) bias[P] = bih[orig] + bhh[orig];
}

// ---------------- helpers ----------------
__device__ __forceinline__ u32x4 ald16(const u16* p) {   // agent-coherent 16B load
  u32x4 r;
  asm volatile("global_load_dwordx4 %0, %1, off sc1" : "=&v"(r) : "v"(p));
  return r;
}
__device__ __forceinline__ u32x4 pld16(const float* p) { // plain cacheable 16B load
  u32x4 r;
  asm volatile("global_load_dwordx4 %0, %1, off" : "=&v"(r) : "v"(p));
  return r;
}
__device__ __forceinline__ void ast2(u16* p, u16 v) {    // agent-coherent 2B store
  asm volatile("global_store_short %0, %1, off sc1" :: "v"(p), "v"((u32)v) : "memory");
}

__device__ __forceinline__ void cvt8(u32x4 a, u32x4 b, bf16x8& hi, bf16x8& lo) {
  #pragma unroll
  for (int j = 0; j < 8; ++j) {
    float f = __uint_as_float(j < 4 ? a[j] : b[j - 4]);
    u16 h = f2bf(f);
    hi[j] = (short)h;
    lo[j] = (short)f2bf(f - bf2f(h));
  }
}

// full-row XOR swizzle (conflict-free, verified round 9)
__device__ __forceinline__ bf16x8 ldB(const u16* base, int r, int k8) {
  return *(const bf16x8*)(base + r * 512 + ((k8 ^ (r & 63)) << 3));
}

// ---------------- persistent LSTM kernel ----------------
// grid 256 = 8 row-groups (m = bid&7) x 32 unit-blocks (nb = bid>>3)
// 512 threads = 8 waves = 4 row-tiles (rt) x 2 K-halves (cp)
__global__ __launch_bounds__(512, 2) void lstm_persistent(
    const float* __restrict__ x,
    const u16* __restrict__ WhhHi, const u16* __restrict__ WhhLo,
    const u16* __restrict__ WihHi, const u16* __restrict__ WihLo,
    const float* __restrict__ bias,
    u16* __restrict__ hPk, u32* __restrict__ fl, float* __restrict__ hT) {
  extern __shared__ char smem[];
  u16* sWhhHi  = (u16*)(smem);
  u16* sWhhLo  = (u16*)(smem + SM_WHH_LO);
  float* sXc   = (float*)(smem + SM_XC);     // 2 buffers x 4096 floats

  const int tid = threadIdx.x;
  const int w = tid >> 6, l = tid & 63;
  const int m  = blockIdx.x & 7;
  const int nb = blockIdx.x >> 3;
  const int Pbase = 64 * nb;
  const int l15 = l & 15, l4 = l >> 4;
  const int rt = w >> 1, cp = w & 1;

  // ---- one-time: resident Whh slice (swizzled r&63) ----
  for (int i = tid; i < 4096; i += 512) {
    int r = i >> 6, k8 = i & 63;
    unsigned dst = r * 512 + ((k8 ^ (r & 63)) << 3);
    *(bf16x8*)(sWhhHi + dst) = *(const bf16x8*)(WhhHi + (size_t)(Pbase + r) * H_ + k8 * 8);
    *(bf16x8*)(sWhhLo + dst) = *(const bf16x8*)(WhhLo + (size_t)(Pbase + r) * H_ + k8 * 8);
  }

  // ---- one-time: bias into registers ----
  float bg4[4];
  #pragma unroll
  for (int g = 0; g < 4; ++g) bg4[g] = bias[Pbase + 16 * g + l15];

  // ---- one-time: Wih fragments into registers (4 col-tiles x 2 k-chunks of this K-half) ----
  bf16x8 wfh[4][2], wfl[4][2];
  #pragma unroll
  for (int ct = 0; ct < 4; ++ct)
    #pragma unroll
    for (int ch = 0; ch < 2; ++ch) {
      int gcol = 16 * ct + l15;
      int k8i = 8 * cp + 4 * ch + l4;
      wfh[ct][ch] = *(const bf16x8*)(WihHi + (size_t)(Pbase + gcol) * F_ + k8i * 8);
      wfl[ct][ch] = *(const bf16x8*)(WihLo + (size_t)(Pbase + gcol) * F_ + k8i * 8);
    }
  __syncthreads();

  const int arow = 64 * m + 16 * rt + l15;

  // prologue: x(0) prefetch (this wave's K-half of F), drained before loop
  u32x4 xa[2], xb[2];
  {
    const float* xr = x + (size_t)arow * T_ * F_ + 64 * cp + 8 * l4;
    xa[0] = pld16(xr);      xb[0] = pld16(xr + 4);
    xa[1] = pld16(xr + 32); xb[1] = pld16(xr + 36);
  }
  asm volatile("s_waitcnt vmcnt(0)" ::: "memory");

  float cr[4] = {0.f, 0.f, 0.f, 0.f};   // cell state, cp0 only, static q-index

  #pragma unroll 1
  for (int t = 0; t < T_; ++t) {
    const u16* hcur = hPk + (size_t)(t & 1) * B_ * H_;
    u16* hnxt = hPk + (size_t)((t & 1) ^ 1) * B_ * H_;
    float* xcb = sXc + (t & 1) * 4096;

    f32x4 acc0 = {0.f,0.f,0.f,0.f}, acc1 = {0.f,0.f,0.f,0.f};
    f32x4 acc2 = {0.f,0.f,0.f,0.f}, acc3 = {0.f,0.f,0.f,0.f};

    // ---- poll the 16 row-matched producer-wave flags of this K-half ----
    if (t > 0 && l < 16) {
      const u32* fp = fl + (size_t)(m * 32 + 16 * cp + l) * 4 + rt;
      long fuse = 400000000;
      while (__hip_atomic_load(fp, __ATOMIC_RELAXED, __HIP_MEMORY_SCOPE_AGENT) < (u32)t) {
        __builtin_amdgcn_s_sleep(1);
        if (--fuse == 0) break;
      }
    }

    // ---- issue ALL 8 h chunks (8 loads, single bf16) upfront ----
    u32x4 Aa[8];
    const u16* hrowt = hcur + (size_t)arow * H_ + 256 * cp + 8 * l4;
    if (t > 0) {
      #pragma unroll
      for (int c = 0; c < 8; ++c) Aa[c] = ald16(hrowt + c * 32);
    }

    // ---- x-part (this K-half of F, 3-term), overlaps h-load flight ----
    #pragma unroll
    for (int ch = 0; ch < 2; ++ch) {
      bf16x8 xh, xl;
      cvt8(xa[ch], xb[ch], xh, xl);
      MFMA16(xh, wfh[0][ch], acc0); MFMA16(xl, wfh[0][ch], acc0); MFMA16(xh, wfl[0][ch], acc0);
      MFMA16(xh, wfh[1][ch], acc1); MFMA16(xl, wfh[1][ch], acc1); MFMA16(xh, wfl[1][ch], acc1);
      MFMA16(xh, wfh[2][ch], acc2); MFMA16(xl, wfh[2][ch], acc2); MFMA16(xh, wfl[2][ch], acc2);
      MFMA16(xh, wfh[3][ch], acc3); MFMA16(xl, wfh[3][ch], acc3); MFMA16(xh, wfl[3][ch], acc3);
    }

    // ---- h-part: 8 K=32 chunks, h A-frag direct from registers (no unpack) ----
    if (t > 0) {
      #pragma unroll
      for (int ch = 0; ch < 8; ++ch) {
        if (ch == 0)      asm volatile("s_waitcnt vmcnt(7)");
        else if (ch == 1) asm volatile("s_waitcnt vmcnt(6)");
        else if (ch == 2) asm volatile("s_waitcnt vmcnt(5)");
        else if (ch == 3) asm volatile("s_waitcnt vmcnt(4)");
        else if (ch == 4) asm volatile("s_waitcnt vmcnt(3)");
        else if (ch == 5) asm volatile("s_waitcnt vmcnt(2)");
        else if (ch == 6) asm volatile("s_waitcnt vmcnt(1)");
        else              asm volatile("s_waitcnt vmcnt(0)");
        __builtin_amdgcn_sched_barrier(0);
        bf16x8 ah = *(const bf16x8*)&Aa[ch];
        int k8 = 32 * cp + 4 * ch + l4;
        bf16x8 bh, bl;
        bh = ldB(sWhhHi, l15, k8);      bl = ldB(sWhhLo, l15, k8);
        MFMA16(ah, bh, acc0); MFMA16(ah, bl, acc0);
        bh = ldB(sWhhHi, 16 + l15, k8); bl = ldB(sWhhLo, 16 + l15, k8);
        MFMA16(ah, bh, acc1); MFMA16(ah, bl, acc1);
        bh = ldB(sWhhHi, 32 + l15, k8); bl = ldB(sWhhLo, 32 + l15, k8);
        MFMA16(ah, bh, acc2); MFMA16(ah, bl, acc2);
        bh = ldB(sWhhHi, 48 + l15, k8); bl = ldB(sWhhLo, 48 + l15, k8);
        MFMA16(ah, bh, acc3); MFMA16(ah, bl, acc3);
      }
    }

    // ---- cp1: publish K-high partials into this step's sXc buffer ----
    if (cp == 1) {
      float* bse = xcb + (rt * 16) * 64 + l;
      bse[0 * 64]  = acc0[0]; bse[1 * 64]  = acc0[1]; bse[2 * 64]  = acc0[2]; bse[3 * 64]  = acc0[3];
      bse[4 * 64]  = acc1[0]; bse[5 * 64]  = acc1[1]; bse[6 * 64]  = acc1[2]; bse[7 * 64]  = acc1[3];
      bse[8 * 64]  = acc2[0]; bse[9 * 64]  = acc2[1]; bse[10 * 64] = acc2[2]; bse[11 * 64] = acc2[3];
      bse[12 * 64] = acc3[0]; bse[13 * 64] = acc3[1]; bse[14 * 64] = acc3[2]; bse[15 * 64] = acc3[3];
    }

    __syncthreads();   // barrier A: partials published (only barrier in the loop)

    if (cp == 1) {
      // ---- cp1: straight to next step; prefetch x(t+1) now ----
      int tp = (t + 1 < T_) ? t + 1 : 0;
      const float* xr = x + (size_t)arow * T_ * F_ + (size_t)tp * F_ + 64 * cp + 8 * l4;
      xa[0] = pld16(xr);      xb[0] = pld16(xr + 4);
      xa[1] = pld16(xr + 32); xb[1] = pld16(xr + 36);
    } else {
      // ---- cp0: fold partials, elementwise (c in VGPRs), bf16 h store, own drain+flag ----
      const float* bse = xcb + (rt * 16) * 64 + l;
      float p[16];
      #pragma unroll
      for (int j = 0; j < 16; ++j) p[j] = bse[j * 64];
      #pragma unroll
      for (int q = 0; q < 4; ++q) {
        float gi = acc0[q] + p[q]      + bg4[0];
        float gf = acc1[q] + p[4 + q]  + bg4[1];
        float gg = acc2[q] + p[8 + q]  + bg4[2];
        float go = acc3[q] + p[12 + q] + bg4[3];
        float ii = 1.f / (1.f + __expf(-gi));
        float ff = 1.f / (1.f + __expf(-gf));
        float gG = 1.f - 2.f / (__expf(2.f * gg) + 1.f);
        float oo = 1.f / (1.f + __expf(-go));
        float c = ff * cr[q] + ii * gG;
        cr[q] = c;
        float h = oo * (1.f - 2.f / (__expf(2.f * c) + 1.f));
        size_t idx = (size_t)(64 * m + 16 * rt + 4 * l4 + q) * H_ + 16 * nb + l15;
        ast2(&hnxt[idx], f2bf(h));
        if (t == T_ - 1) hT[idx] = h;
      }
      asm volatile("s_waitcnt vmcnt(0)" ::: "memory");   // drain only the 4 h stores
      if (l == 0)
        __hip_atomic_store(&fl[(size_t)(m * 32 + nb) * 4 + rt], (u32)(t + 1),
                           __ATOMIC_RELAXED, __HIP_MEMORY_SCOPE_AGENT);
      // x(t+1) prefetch after the flag so the drain doesn't wait on it
      int tp = (t + 1 < T_) ? t + 1 : 0;
      const float* xr = x + (size_t)arow * T_ * F_ + (size_t)tp * F_ + 64 * cp + 8 * l4;
      xa[0] = pld16(xr);      xb[0] = pld16(xr + 4);
      xa[1] = pld16(xr + 32); xb[1] = pld16(xr + 36);
    }
  }
}

// ---------------- head: z = relu(hT @ W1^T + b1) ----------------
__global__ __launch_bounds__(256) void head1(const float* __restrict__ hT,
                                             const float* __restrict__ W1,
                                             const float* __restrict__ b1,
                                             float* __restrict__ z) {
  __shared__ float sA[64][16];
  __shared__ float sBt[16][64];
  int tx = threadIdx.x & 15, ty = threadIdx.x >> 4;
  int row0 = blockIdx.y * 64, col0 = blockIdx.x * 64;
  float acc[4][4] = {};
  for (int k0 = 0; k0 < H_; k0 += 16) {
    int c = threadIdx.x >> 2, kk4 = (threadIdx.x & 3) * 4;
    float4 av = *(const float4*)(hT + (size_t)(row0 + c) * H_ + k0 + kk4);
    *(float4*)&sA[c][kk4] = av;
    float4 bv = *(const float4*)(W1 + (size_t)(col0 + c) * H_ + k0 + kk4);
    sBt[kk4 + 0][c] = bv.x; sBt[kk4 + 1][c] = bv.y;
    sBt[kk4 + 2][c] = bv.z; sBt[kk4 + 3][c] = bv.w;
    __syncthreads();
    #pragma unroll
    for (int kk = 0; kk < 16; ++kk) {
      float a0 = sA[ty * 4 + 0][kk], a1 = sA[ty * 4 + 1][kk];
      float a2 = sA[ty * 4 + 2][kk], a3 = sA[ty * 4 + 3][kk];
      float b0 = sBt[kk][tx * 4 + 0], b1v = sBt[kk][tx * 4 + 1];
      float b2v = sBt[kk][tx * 4 + 2], b3 = sBt[kk][tx * 4 + 3];
      acc[0][0] += a0 * b0; acc[0][1] += a0 * b1v; acc[0][2] += a0 * b2v; acc[0][3] += a0 * b3;
      acc[1][0] += a1 * b0; acc[1][1] += a1 * b1v; acc[1][2] += a1 * b2v; acc[1][3] += a1 * b3;
      acc[2][0] += a2 * b0; acc[2][1] += a2 * b1v; acc[2][2] += a2 * b2v; acc[2][3] += a2 * b3;
      acc[3][0] += a3 * b0; acc[3][1] += a3 * b1v; acc[3][2] += a3 * b2v; acc[3][3] += a3 * b3;
    }
    __syncthreads();
  }
  #pragma unroll
  for (int i = 0; i < 4; ++i)
    #pragma unroll
    for (int j = 0; j < 4; ++j) {
      int rr = row0 + ty * 4 + i, cc = col0 + tx * 4 + j;
      float v = acc[i][j] + b1[cc];
      z[(size_t)rr * LH_ + cc] = v > 0.f ? v : 0.f;
    }
}

// ---------------- head: out[b] = z[b,:] . W2 + b2 ----------------
__global__ __launch_bounds__(256) void head2(const float* __restrict__ z,
                                             const float* __restrict__ W2,
                                             const float* __restrict__ b2,
                                             float* __restrict__ out) {
  int b = blockIdx.x;
  float p = 0.f;
  for (int j = threadIdx.x; j < LH_; j += 256) p += z[(size_t)b * LH_ + j] * W2[j];
  #pragma unroll
  for (int off = 32; off > 0; off >>= 1) p += __shfl_down(p, off);
  __shared__ float red[4];
  if ((threadIdx.x & 63) == 0) red[threadIdx.x >> 6] = p;
  __syncthreads();
  if (threadIdx.x == 0) out[b] = red[0] + red[1] + red[2] + red[3] + b2[0];
}

// ---------------- launch ----------------
extern "C" void kernel_launch(void* const* d_in, const int* in_sizes, int n_in,
                              void* d_out, int out_size, void* d_ws, size_t ws_size,
                              hipStream_t stream) {
  const float* x    = (const float*)d_in[0];
  const float* Wih  = (const float*)d_in[1];
  const float* Whh  = (const float*)d_in[2];
  const float* bih  = (const float*)d_in[3];
  const float* bhh  = (const float*)d_in[4];
  const float* W1   = (const float*)d_in[5];
  const float* b1   = (const float*)d_in[6];
  const float* W2   = (const float*)d_in[7];
  const float* b2   = (const float*)d_in[8];

  char* ws = (char*)d_ws;
  u16* hPk      = (u16*)(ws + O_HPK);
  u32* fl       = (u32*)(ws + O_FL);
  u16* whhHi    = (u16*)(ws + O_WHH_HI);
  u16* whhLo    = (u16*)(ws + O_WHH_LO);
  u16* wihHi    = (u16*)(ws + O_WIH_HI);
  u16* wihLo    = (u16*)(ws + O_WIH_LO);
  float* bias   = (float*)(ws + O_BIAS);
  float* hT     = (float*)(ws + O_HT);
  float* zbuf   = (float*)(ws + O_Z);

  (void)hipMemsetAsync(ws, 0, O_MSET, stream);

  prep_weights<<<G_, 128, 0, stream>>>(Wih, Whh, bih, bhh, whhHi, whhLo, wihHi, wihLo, bias);

  (void)hipFuncSetAttribute((const void*)lstm_persistent,
                            hipFuncAttributeMaxDynamicSharedMemorySize, SMEM_BYTES);

  lstm_persistent<<<256, 512, SMEM_BYTES, stream>>>(x, whhHi, whhLo, wihHi, wihLo,
                                                    bias, hPk, fl, hT);

  head1<<<dim3(LH_ / 64, B_ / 64), 256, 0, stream>>>(hT, W1, b1, zbuf);
  head2<<<B_, 256, 0, stream>>>(zbuf, W2, b2, (float*)d_out);
}

// Round 15
// 6926.941 us; speedup vs baseline: 4.2597x; 2.0268x over previous
//
#include <hip/hip_runtime.h>

typedef unsigned short u16;
typedef unsigned int u32;
typedef __attribute__((ext_vector_type(8))) short bf16x8;
typedef __attribute__((ext_vector_type(4))) float f32x4;
typedef __attribute__((ext_vector_type(4))) unsigned int u32x4;

#define B_ 512
#define T_ 1024
#define F_ 128
#define H_ 512
#define G_ 2048
#define LH_ 1024

#define MFMA16(a,b,c) (c) = __builtin_amdgcn_mfma_f32_16x16x32_bf16((a),(b),(c),0,0,0)

__device__ __forceinline__ u16 f2bf(float f) {
  unsigned u = __float_as_uint(f);
  unsigned r = (u + 0x7fffu + ((u >> 16) & 1u)) >> 16;
  return (u16)r;
}
__device__ __forceinline__ float bf2f(u16 h) {
  return __uint_as_float(((unsigned)h) << 16);
}

// ---------------- workspace layout (bytes) ----------------
constexpr size_t O_HPK     = 0;                               // bf16 h, 2 bufs: 1 MB
constexpr size_t O_FL      = O_HPK + (size_t)2 * B_ * H_ * 2; // per-wg step flags
constexpr size_t O_MSET    = O_FL + 4096;                     // memset [0, O_MSET)
constexpr size_t O_WHH_HI  = O_MSET;
constexpr size_t O_WHH_LO  = O_WHH_HI + (size_t)G_ * H_ * 2;
constexpr size_t O_WIH_HI  = O_WHH_LO + (size_t)G_ * H_ * 2;
constexpr size_t O_WIH_LO  = O_WIH_HI + (size_t)G_ * F_ * 2;
constexpr size_t O_BIAS    = O_WIH_LO + (size_t)G_ * F_ * 2;
constexpr size_t O_HT      = O_BIAS + (size_t)G_ * 4;
constexpr size_t O_Z       = O_HT + (size_t)B_ * H_ * 4;

// ---------------- LDS layout (identical to round 9) ----------------
constexpr unsigned SM_WHH_LO = 65536;    // sWhhHi [64][512] u16 swizzled at 0
constexpr unsigned SM_XC     = 131072;   // partial-acc exchange [4 rt][16 j][64 l] f32 = 16 KB
constexpr unsigned SM_BIAS   = 147456;   // f32[64]
constexpr unsigned SMEM_BYTES = 147712;

// ---------------- weight prep: permute + split to hi/lo bf16 ----------------
// permuted gate-col P = 64*nb + 16*g + u'  (unit u = 16*nb + u', g in {i,f,g,o})
__global__ void prep_weights(const float* __restrict__ Wih, const float* __restrict__ Whh,
                             const float* __restrict__ bih, const float* __restrict__ bhh,
                             u16* __restrict__ WhhHi, u16* __restrict__ WhhLo,
                             u16* __restrict__ WihHi, u16* __restrict__ WihLo,
                             float* __restrict__ bias) {
  int P = blockIdx.x;
  int nb = P >> 6, g = (P >> 4) & 3, u = P & 15;
  int orig = g * H_ + (nb << 4) + u;
  for (int k = threadIdx.x; k < H_; k += 128) {
    float w = Whh[(size_t)orig * H_ + k];
    u16 hi = f2bf(w);
    WhhHi[(size_t)P * H_ + k] = hi;
    WhhLo[(size_t)P * H_ + k] = f2bf(w - bf2f(hi));
  }
  {
    int k = threadIdx.x;
    float w = Wih[(size_t)orig * F_ + k];
    u16 hi = f2bf(w);
    WihHi[(size_t)P * F_ + k] = hi;
    WihLo[(size_t)P * F_ + k] = f2bf(w - bf2f(hi));
  }
  if (threadIdx.x == 0) bias[P] = bih[orig] + bhh[orig];
}

// ---------------- helpers ----------------
__device__ __forceinline__ u32x4 ald16(const u16* p) {   // agent-coherent 16B load
  u32x4 r;
  asm volatile("global_load_dwordx4 %0, %1, off sc1" : "=&v"(r) : "v"(p));
  return r;
}
__device__ __forceinline__ u32x4 pld16(const float* p) { // plain cacheable 16B load
  u32x4 r;
  asm volatile("global_load_dwordx4 %0, %1, off" : "=&v"(r) : "v"(p));
  return r;
}
__device__ __forceinline__ void ast2(u16* p, u16 v) {    // agent-coherent 2B store
  asm volatile("global_store_short %0, %1, off sc1" :: "v"(p), "v"((u32)v) : "memory");
}

__device__ __forceinline__ void cvt8(u32x4 a, u32x4 b, bf16x8& hi, bf16x8& lo) {
  #pragma unroll
  for (int j = 0; j < 8; ++j) {
    float f = __uint_as_float(j < 4 ? a[j] : b[j - 4]);
    u16 h = f2bf(f);
    hi[j] = (short)h;
    lo[j] = (short)f2bf(f - bf2f(h));
  }
}

// full-row XOR swizzle (conflict-free, verified round 9)
__device__ __forceinline__ bf16x8 ldB(const u16* base, int r, int k8) {
  return *(const bf16x8*)(base + r * 512 + ((k8 ^ (r & 63)) << 3));
}

// ---------------- persistent LSTM kernel ----------------
// grid 256 = 8 row-groups (m = bid&7) x 32 unit-blocks (nb = bid>>3)
// 512 threads = 8 waves = 4 row-tiles (rt) x 2 K-halves (cp)
// sync skeleton IDENTICAL to round 9 (proven 9.12 ms); h exchange = single bf16
__global__ __launch_bounds__(512, 2) void lstm_persistent(
    const float* __restrict__ x,
    const u16* __restrict__ WhhHi, const u16* __restrict__ WhhLo,
    const u16* __restrict__ WihHi, const u16* __restrict__ WihLo,
    const float* __restrict__ bias,
    u16* __restrict__ hPk, u32* __restrict__ fl, float* __restrict__ hT) {
  extern __shared__ char smem[];
  u16* sWhhHi  = (u16*)(smem);
  u16* sWhhLo  = (u16*)(smem + SM_WHH_LO);
  float* sXc   = (float*)(smem + SM_XC);
  float* sBias = (float*)(smem + SM_BIAS);

  const int tid = threadIdx.x;
  const int w = tid >> 6, l = tid & 63;
  const int m  = blockIdx.x & 7;
  const int nb = blockIdx.x >> 3;
  const int Pbase = 64 * nb;
  const int l15 = l & 15, l4 = l >> 4;
  const int rt = w >> 1, cp = w & 1;

  // ---- one-time: resident Whh slice (swizzled r&63), bias ----
  for (int i = tid; i < 4096; i += 512) {
    int r = i >> 6, k8 = i & 63;
    unsigned dst = r * 512 + ((k8 ^ (r & 63)) << 3);
    *(bf16x8*)(sWhhHi + dst) = *(const bf16x8*)(WhhHi + (size_t)(Pbase + r) * H_ + k8 * 8);
    *(bf16x8*)(sWhhLo + dst) = *(const bf16x8*)(WhhLo + (size_t)(Pbase + r) * H_ + k8 * 8);
  }
  if (tid < 64) sBias[tid] = bias[Pbase + tid];

  // ---- one-time: Wih fragments into registers (4 col-tiles x 2 k-chunks of this K-half) ----
  bf16x8 wfh[4][2], wfl[4][2];
  #pragma unroll
  for (int ct = 0; ct < 4; ++ct)
    #pragma unroll
    for (int ch = 0; ch < 2; ++ch) {
      int gcol = 16 * ct + l15;
      int k8i = 8 * cp + 4 * ch + l4;
      wfh[ct][ch] = *(const bf16x8*)(WihHi + (size_t)(Pbase + gcol) * F_ + k8i * 8);
      wfl[ct][ch] = *(const bf16x8*)(WihLo + (size_t)(Pbase + gcol) * F_ + k8i * 8);
    }
  __syncthreads();

  const float bi = sBias[l15], bf_ = sBias[16 + l15], bg = sBias[32 + l15], bo = sBias[48 + l15];
  const int arow = 64 * m + 16 * rt + l15;

  // prologue: x(0) prefetch (this wave's K-half of F), drained before loop
  u32x4 xa[2], xb[2];
  {
    const float* xr = x + (size_t)arow * T_ * F_ + 64 * cp + 8 * l4;
    xa[0] = pld16(xr);      xb[0] = pld16(xr + 4);
    xa[1] = pld16(xr + 32); xb[1] = pld16(xr + 36);
  }
  asm volatile("s_waitcnt vmcnt(0)" ::: "memory");

  float cr[4] = {0.f, 0.f, 0.f, 0.f};   // cell state, cp0 only, static q-index

  #pragma unroll 1
  for (int t = 0; t < T_; ++t) {
    const u16* hcur = hPk + (size_t)(t & 1) * B_ * H_;
    u16* hnxt = hPk + (size_t)((t & 1) ^ 1) * B_ * H_;

    f32x4 acc0 = {0.f,0.f,0.f,0.f}, acc1 = {0.f,0.f,0.f,0.f};
    f32x4 acc2 = {0.f,0.f,0.f,0.f}, acc3 = {0.f,0.f,0.f,0.f};

    // ---- per-wave poll: this K-half's 16 producer wgs (lanes 0..15), AGENT scope ----
    if (t > 0 && l < 16) {
      const u32* fp = fl + m * 32 + 16 * cp + l;
      long fuse = 400000000;
      while (__hip_atomic_load(fp, __ATOMIC_RELAXED, __HIP_MEMORY_SCOPE_AGENT) < (u32)t) {
        __builtin_amdgcn_s_sleep(1);
        if (--fuse == 0) break;
      }
    }

    // ---- issue ALL 8 h chunks (8 loads, single bf16) upfront ----
    u32x4 Aa[8];
    const u16* hrowt = hcur + (size_t)arow * H_ + 256 * cp + 8 * l4;
    if (t > 0) {
      #pragma unroll
      for (int c = 0; c < 8; ++c) Aa[c] = ald16(hrowt + c * 32);
    }

    // ---- x-part (this K-half of F, 3-term split), overlaps h-load flight ----
    #pragma unroll
    for (int ch = 0; ch < 2; ++ch) {
      bf16x8 xh, xl;
      cvt8(xa[ch], xb[ch], xh, xl);
      MFMA16(xh, wfh[0][ch], acc0); MFMA16(xl, wfh[0][ch], acc0); MFMA16(xh, wfl[0][ch], acc0);
      MFMA16(xh, wfh[1][ch], acc1); MFMA16(xl, wfh[1][ch], acc1); MFMA16(xh, wfl[1][ch], acc1);
      MFMA16(xh, wfh[2][ch], acc2); MFMA16(xl, wfh[2][ch], acc2); MFMA16(xh, wfl[2][ch], acc2);
      MFMA16(xh, wfh[3][ch], acc3); MFMA16(xl, wfh[3][ch], acc3); MFMA16(xh, wfl[3][ch], acc3);
    }

    // ---- h-part: 8 K=32 chunks, A-frag direct from loaded regs (no unpack) ----
    if (t > 0) {
      #pragma unroll
      for (int ch = 0; ch < 8; ++ch) {
        if (ch == 0)      asm volatile("s_waitcnt vmcnt(7)");
        else if (ch == 1) asm volatile("s_waitcnt vmcnt(6)");
        else if (ch == 2) asm volatile("s_waitcnt vmcnt(5)");
        else if (ch == 3) asm volatile("s_waitcnt vmcnt(4)");
        else if (ch == 4) asm volatile("s_waitcnt vmcnt(3)");
        else if (ch == 5) asm volatile("s_waitcnt vmcnt(2)");
        else if (ch == 6) asm volatile("s_waitcnt vmcnt(1)");
        else              asm volatile("s_waitcnt vmcnt(0)");
        __builtin_amdgcn_sched_barrier(0);
        bf16x8 ah = *(const bf16x8*)&Aa[ch];
        int k8 = 32 * cp + 4 * ch + l4;
        bf16x8 bh, bl;
        bh = ldB(sWhhHi, l15, k8);      bl = ldB(sWhhLo, l15, k8);
        MFMA16(ah, bh, acc0); MFMA16(ah, bl, acc0);
        bh = ldB(sWhhHi, 16 + l15, k8); bl = ldB(sWhhLo, 16 + l15, k8);
        MFMA16(ah, bh, acc1); MFMA16(ah, bl, acc1);
        bh = ldB(sWhhHi, 32 + l15, k8); bl = ldB(sWhhLo, 32 + l15, k8);
        MFMA16(ah, bh, acc2); MFMA16(ah, bl, acc2);
        bh = ldB(sWhhHi, 48 + l15, k8); bl = ldB(sWhhLo, 48 + l15, k8);
        MFMA16(ah, bh, acc3); MFMA16(ah, bl, acc3);
      }
    }

    // ---- cp1: publish K-high partials (conflict-free transposed layout) ----
    if (cp == 1) {
      float* bse = sXc + (rt * 16) * 64 + l;
      bse[0 * 64]  = acc0[0]; bse[1 * 64]  = acc0[1]; bse[2 * 64]  = acc0[2]; bse[3 * 64]  = acc0[3];
      bse[4 * 64]  = acc1[0]; bse[5 * 64]  = acc1[1]; bse[6 * 64]  = acc1[2]; bse[7 * 64]  = acc1[3];
      bse[8 * 64]  = acc2[0]; bse[9 * 64]  = acc2[1]; bse[10 * 64] = acc2[2]; bse[11 * 64] = acc2[3];
      bse[12 * 64] = acc3[0]; bse[13 * 64] = acc3[1]; bse[14 * 64] = acc3[2]; bse[15 * 64] = acc3[3];
    }

    __syncthreads();   // A: partials published

    // ---- x(t+1) prefetch (drains at step-end vmcnt(0)) ----
    {
      int tp = (t + 1 < T_) ? t + 1 : 0;
      const float* xr = x + (size_t)arow * T_ * F_ + (size_t)tp * F_ + 64 * cp + 8 * l4;
      xa[0] = pld16(xr);      xb[0] = pld16(xr + 4);
      xa[1] = pld16(xr + 32); xb[1] = pld16(xr + 36);
    }

    // ---- cp0: fold partials, elementwise update (c in VGPRs), bf16 AGENT h store ----
    if (cp == 0) {
      const float* bse = sXc + (rt * 16) * 64 + l;
      float p[16];
      #pragma unroll
      for (int j = 0; j < 16; ++j) p[j] = bse[j * 64];
      #pragma unroll
      for (int q = 0; q < 4; ++q) {
        float gi = acc0[q] + p[q]      + bi;
        float gf = acc1[q] + p[4 + q]  + bf_;
        float gg = acc2[q] + p[8 + q]  + bg;
        float go = acc3[q] + p[12 + q] + bo;
        float ii = 1.f / (1.f + __expf(-gi));
        float ff = 1.f / (1.f + __expf(-gf));
        float gG = 1.f - 2.f / (__expf(2.f * gg) + 1.f);
        float oo = 1.f / (1.f + __expf(-go));
        float c = ff * cr[q] + ii * gG;
        cr[q] = c;
        float h = oo * (1.f - 2.f / (__expf(2.f * c) + 1.f));
        size_t idx = (size_t)(64 * m + 16 * rt + 4 * l4 + q) * H_ + 16 * nb + l15;
        ast2(&hnxt[idx], f2bf(h));
        if (t == T_ - 1) hT[idx] = h;
      }
    }

    // ---- drain (per wave), barrier, single AGENT flag store, isolate from vmcnt ----
    asm volatile("s_waitcnt vmcnt(0)" ::: "memory");
    __syncthreads();   // B
    if (tid == 0) {
      __hip_atomic_store(&fl[m * 32 + nb], (u32)(t + 1), __ATOMIC_RELAXED, __HIP_MEMORY_SCOPE_AGENT);
      asm volatile("s_waitcnt vmcnt(0)" ::: "memory");
    }
  }
}

// ---------------- head: z = relu(hT @ W1^T + b1) ----------------
__global__ __launch_bounds__(256) void head1(const float* __restrict__ hT,
                                             const float* __restrict__ W1,
                                             const float* __restrict__ b1,
                                             float* __restrict__ z) {
  __shared__ float sA[64][16];
  __shared__ float sBt[16][64];
  int tx = threadIdx.x & 15, ty = threadIdx.x >> 4;
  int row0 = blockIdx.y * 64, col0 = blockIdx.x * 64;
  float acc[4][4] = {};
  for (int k0 = 0; k0 < H_; k0 += 16) {
    int c = threadIdx.x >> 2, kk4 = (threadIdx.x & 3) * 4;
    float4 av = *(const float4*)(hT + (size_t)(row0 + c) * H_ + k0 + kk4);
    *(float4*)&sA[c][kk4] = av;
    float4 bv = *(const float4*)(W1 + (size_t)(col0 + c) * H_ + k0 + kk4);
    sBt[kk4 + 0][c] = bv.x; sBt[kk4 + 1][c] = bv.y;
    sBt[kk4 + 2][c] = bv.z; sBt[kk4 + 3][c] = bv.w;
    __syncthreads();
    #pragma unroll
    for (int kk = 0; kk < 16; ++kk) {
      float a0 = sA[ty * 4 + 0][kk], a1 = sA[ty * 4 + 1][kk];
      float a2 = sA[ty * 4 + 2][kk], a3 = sA[ty * 4 + 3][kk];
      float b0 = sBt[kk][tx * 4 + 0], b1v = sBt[kk][tx * 4 + 1];
      float b2v = sBt[kk][tx * 4 + 2], b3 = sBt[kk][tx * 4 + 3];
      acc[0][0] += a0 * b0; acc[0][1] += a0 * b1v; acc[0][2] += a0 * b2v; acc[0][3] += a0 * b3;
      acc[1][0] += a1 * b0; acc[1][1] += a1 * b1v; acc[1][2] += a1 * b2v; acc[1][3] += a1 * b3;
      acc[2][0] += a2 * b0; acc[2][1] += a2 * b1v; acc[2][2] += a2 * b2v; acc[2][3] += a2 * b3;
      acc[3][0] += a3 * b0; acc[3][1] += a3 * b1v; acc[3][2] += a3 * b2v; acc[3][3] += a3 * b3;
    }
    __syncthreads();
  }
  #pragma unroll
  for (int i = 0; i < 4; ++i)
    #pragma unroll
    for (int j = 0; j < 4; ++j) {
      int rr = row0 + ty * 4 + i, cc = col0 + tx * 4 + j;
      float v = acc[i][j] + b1[cc];
      z[(size_t)rr * LH_ + cc] = v > 0.f ? v : 0.f;
    }
}

// ---------------- head: out[b] = z[b,:] . W2 + b2 ----------------
__global__ __launch_bounds__(256) void head2(const float* __restrict__ z,
                                             const float* __restrict__ W2,
                                             const float* __restrict__ b2,
                                             float* __restrict__ out) {
  int b = blockIdx.x;
  float p = 0.f;
  for (int j = threadIdx.x; j < LH_; j += 256) p += z[(size_t)b * LH_ + j] * W2[j];
  #pragma unroll
  for (int off = 32; off > 0; off >>= 1) p += __shfl_down(p, off);
  __shared__ float red[4];
  if ((threadIdx.x & 63) == 0) red[threadIdx.x >> 6] = p;
  __syncthreads();
  if (threadIdx.x == 0) out[b] = red[0] + red[1] + red[2] + red[3] + b2[0];
}

// ---------------- launch ----------------
extern "C" void kernel_launch(void* const* d_in, const int* in_sizes, int n_in,
                              void* d_out, int out_size, void* d_ws, size_t ws_size,
                              hipStream_t stream) {
  const float* x    = (const float*)d_in[0];
  const float* Wih  = (const float*)d_in[1];
  const float* Whh  = (const float*)d_in[2];
  const float* bih  = (const float*)d_in[3];
  const float* bhh  = (const float*)d_in[4];
  const float* W1   = (const float*)d_in[5];
  const float* b1   = (const float*)d_in[6];
  const float* W2   = (const float*)d_in[7];
  const float* b2   = (const float*)d_in[8];

  char* ws = (char*)d_ws;
  u16* hPk      = (u16*)(ws + O_HPK);
  u32* fl       = (u32*)(ws + O_FL);
  u16* whhHi    = (u16*)(ws + O_WHH_HI);
  u16* whhLo    = (u16*)(ws + O_WHH_LO);
  u16* wihHi    = (u16*)(ws + O_WIH_HI);
  u16* wihLo    = (u16*)(ws + O_WIH_LO);
  float* bias   = (float*)(ws + O_BIAS);
  float* hT     = (float*)(ws + O_HT);
  float* zbuf   = (float*)(ws + O_Z);

  (void)hipMemsetAsync(ws, 0, O_MSET, stream);

  prep_weights<<<G_, 128, 0, stream>>>(Wih, Whh, bih, bhh, whhHi, whhLo, wihHi, wihLo, bias);

  (void)hipFuncSetAttribute((const void*)lstm_persistent,
                            hipFuncAttributeMaxDynamicSharedMemorySize, SMEM_BYTES);

  lstm_persistent<<<256, 512, SMEM_BYTES, stream>>>(x, whhHi, whhLo, wihHi, wihLo,
                                                    bias, hPk, fl, hT);

  head1<<<dim3(LH_ / 64, B_ / 64), 256, 0, stream>>>(hT, W1, b1, zbuf);
  head2<<<B_, 256, 0, stream>>>(zbuf, W2, b2, (float*)d_out);
}